// Round 7
// baseline (6812.569 us; speedup 1.0000x reference)
//
#include <hip/hip_runtime.h>
#include <math.h>

// ESN reservoir, persistent kernel, round 25: r24 + three local fixes.
//
// r24 post-mortem (6683us, best): conflicts only 8.6e8->2.9e8 because the
// W swizzle was on granule bits 1-3 (32B stride): 8 slots x 32B = 256B maps
// onto only HALF the banks ({0-3,8-11,16-19,24-27}) => 2x the b128 minimum.
// Fix: XOR on bits 0-2 (16B stride, 8 slots = 128B = all 32 banks).
// Step still ~7830cy with ~1940cy VALU: detect pays ~1-1.5 UC RT per step
// (poll = issue->RT->check even when data already visible) and the
// post-barrier final loads Win/x from global on the recurrence chain.
//
// r25 changes (only these):
//  1. W LDS swizzle: slot = granule ^ ((row>>3)&7)  [bits 0-2]. Read lanes
//     map (2*kslot)^rgrp uniformly over all 8 bank-quads = conflict-free.
//  2. Check-first poll + cross-step prefetch: ta/tb live across steps;
//     next step's tagged loads issued right after this step's stores
//     (pattern r22 validated for correctness); loop top = vmcnt(0) + reg
//     check first. Prefetch hit => detect ~0; miss => unchanged. Tag check
//     absorbs staleness; single gate per step.
//  3. Win hoisted to regs before the t-loop (loop-invariant per thread);
//     x[b,t,:] prefetched before the dot => post-barrier chain pure VALU.
//
// Everything else r24-verbatim: tagged protocol (dword = 2x int8 + tag16;
// dword-store atomicity certifies payload), per-lane single-producer poll,
// k-split waves, ONE __syncthreads/step, waves 0-1 final+tanh+tagged
// stores, waves 2-7 rotating projection, parity double-buffered red/hstage,
// bounded spins (never hang), int32 dot exact => bit-identical h trajectory.

#define RDIM   2048
#define BATCH  16
#define TSTEPS 2048
#define NIN    3
#define NOUT   3
#define NBLK   256
#define NTHR   512

typedef unsigned u32x2 __attribute__((ext_vector_type(2)));

// workspace layout (dwords)
#define HT0_DW     0            // [8 groups][2 batches][1024] tagged h dwords
#define HT1_DW     16384
#define WS_USED_DW 32768

#define POLL_MAX   (1L << 16)

__device__ __forceinline__ void st1_uc(unsigned* p, unsigned v) {
    asm volatile("global_store_dword %0, %1, off sc0 sc1" :: "v"(p), "v"(v) : "memory");
}

__device__ __forceinline__ int q8(float v) {          // round, clamp [-127,127]
    float c = fminf(127.f, fmaxf(-127.f, v));
    return (int)__builtin_rintf(c);
}
__device__ __forceinline__ unsigned pack4(int a, int b, int c, int d) {
    return (a & 0xff) | ((b & 0xff) << 8) | ((c & 0xff) << 16) | ((d & 0xff) << 24);
}
__device__ __forceinline__ int dot4i(unsigned a, unsigned b, int c) {
#if __has_builtin(__builtin_amdgcn_sdot4)
    return __builtin_amdgcn_sdot4((int)a, (int)b, c, false);
#else
    c += (int)(signed char)(a) * (int)(signed char)(b);
    c += (int)(signed char)(a >> 8)  * (int)(signed char)(b >> 8);
    c += (int)(signed char)(a >> 16) * (int)(signed char)(b >> 16);
    c += (int)(signed char)(a >> 24) * (int)(signed char)(b >> 24);
    return c;
#endif
}
__device__ __forceinline__ int dot16(uint4 wq, uint4 hq, int c) {
    c = dot4i(wq.x, hq.x, c);
    c = dot4i(wq.y, hq.y, c);
    c = dot4i(wq.z, hq.z, c);
    c = dot4i(wq.w, hq.w, c);
    return c;
}

extern "C" __global__ void __launch_bounds__(NTHR, 1) esn_persist(
    const float* __restrict__ W,       // [R,R] fp32
    const float* __restrict__ Win,     // [R,3]
    const float* __restrict__ x,       // [B,T,3]
    const float* __restrict__ Wout,    // [3,R]
    const float* __restrict__ bout,    // [3]
    unsigned* wsu,                     // workspace (dwords, see layout)
    float* __restrict__ out)           // [B,T,3]
{
    __shared__ int red[2][8][8][17];               // [par][wave][rgrp][rr*2+b] padded
    __shared__ __align__(16) unsigned hstage[2][2][512];  // [par][batch][payload dw]
    __shared__ float wscale[64];                   // per-row W scale (m/127)
    extern __shared__ unsigned wlds[];             // 128 KB: W int8, swizzled granules

    const int tid  = threadIdx.x;
    const int lane = tid & 63;
    const int w    = tid >> 6;               // wave 0..7
    const int blk  = blockIdx.x;
    const int rg   = blk & 31;               // rows rg*64..+64
    const int g    = blk >> 5;               // batches g*2..+2
    const int b0    = g * 2;
    const int kslot = lane >> 3;             // 0..7: k sub-slice within wave
    const int rgrp  = lane & 7;              // 0..7: row octet within block

    // ---- one-time: quantize W rows -> LDS int8 (per-row scale), swizzled ----
    // granule G of in-block row r stored at slot G ^ ((r>>3)&7); here r>>3 == w.
    // 16B slot stride => 8 slots tile 128B = all 32 banks (r24 used 32B stride
    // = half the banks = 2x b128 minimum).
#pragma unroll
    for (int rr = 0; rr < 8; ++rr) {
        const int   row = rg * 64 + w * 8 + rr;
        const float4* Wr = (const float4*)(W + (size_t)row * RDIM);
        float m = 0.f;
#pragma unroll
        for (int j = 0; j < 8; ++j) {        // lane covers 8 float4 = 32 elems
            float4 v = Wr[j * 64 + lane];
            m = fmaxf(m, fmaxf(fmaxf(fabsf(v.x), fabsf(v.y)),
                               fmaxf(fabsf(v.z), fabsf(v.w))));
        }
#pragma unroll
        for (int off = 32; off >= 1; off >>= 1)
            m = fmaxf(m, __shfl_xor(m, off, 64));
        const float inv = (m > 0.f) ? 127.f / m : 0.f;
        if (lane == 0) wscale[w * 8 + rr] = (m > 0.f) ? m / 127.f : 0.f;
#pragma unroll
        for (int j = 0; j < 8; ++j) {
            float4 v = Wr[j * 64 + lane];
            const int gsw = (j * 16 + (lane >> 2)) ^ w;          // bits 0-2 XOR
            wlds[(w * 8 + rr) * 512 + gsw * 4 + (lane & 3)] =
                pack4(q8(v.x * inv), q8(v.y * inv), q8(v.z * inv), q8(v.w * inv));
        }
    }

    // ---- hoist Win (loop-invariant per final-thread) ----
    float wn0 = 0.f, wn1 = 0.f, wn2 = 0.f;
    if (tid < 128) {
        const float* wp = Win + (size_t)(rg * 64 + (tid >> 1)) * NIN;
        wn0 = wp[0]; wn1 = wp[1]; wn2 = wp[2];
    }
    __syncthreads();

    unsigned* const ht0 = wsu + HT0_DW;
    unsigned* const ht1 = wsu + HT1_DW;

    // persistent poll regs; bootstrap prefetch (memset zeros = tag0 = h0)
    u32x2 ta, tb;
    {
        const unsigned* pA0 = ht0 + g * 2048 +        128 * w + 2 * lane;
        const unsigned* pB0 = ht0 + g * 2048 + 1024 + 128 * w + 2 * lane;
        asm volatile("global_load_dwordx2 %0, %2, off sc0 sc1\n\t"
                     "global_load_dwordx2 %1, %3, off sc0 sc1"
                     : "=&v"(ta), "=&v"(tb) : "v"(pA0), "v"(pB0) : "memory");
    }

    for (int t = 0; t <= TSTEPS; ++t) {
        unsigned* const hb  = (t & 1) ? ht1 : ht0;   // tags == t live here
        unsigned* const hbn = (t & 1) ? ht0 : ht1;   // t+1 stores go here
        const unsigned tg  = (unsigned)t & 0xffffu;
        const unsigned tg1 = (unsigned)(t + 1) & 0xffffu;
        const int par = t & 1;

        // ---- poll: check-first on prefetched regs; reload only on miss ----
        {
            const unsigned* pA = hb + g * 2048 +        128 * w + 2 * lane;
            const unsigned* pB = hb + g * 2048 + 1024 + 128 * w + 2 * lane;
            asm volatile("s_waitcnt vmcnt(0)" : "+v"(ta), "+v"(tb) :: "memory");
            long r = 0;
            for (;;) {
                bool ok = (ta[0] >> 16) == tg && (ta[1] >> 16) == tg &&
                          (tb[0] >> 16) == tg && (tb[1] >> 16) == tg;
                if (ok || r > POLL_MAX) break;   // per-lane exit; never hangs
                ++r;
                if (r > 64) __builtin_amdgcn_s_sleep(1);
                asm volatile("global_load_dwordx2 %0, %2, off sc0 sc1\n\t"
                             "global_load_dwordx2 %1, %3, off sc0 sc1\n\t"
                             "s_waitcnt vmcnt(0)"
                             : "=&v"(ta), "=&v"(tb) : "v"(pA), "v"(pB) : "memory");
            }
        }
        // detag: payload dword (4 int8 h values) per batch -> hstage
        const unsigned pdA = (ta[0] & 0xffffu) | (ta[1] << 16);
        const unsigned pdB = (tb[0] & 0xffffu) | (tb[1] << 16);
        hstage[par][0][(w << 6) + lane] = pdA;
        hstage[par][1][(w << 6) + lane] = pdB;

        // ---- x prefetch for the post-barrier final (off the chain) ----
        float xv0 = 0.f, xv1 = 0.f, xv2 = 0.f;
        if (t < TSTEPS && tid < 128) {
            const float* xp = x + ((size_t)(b0 + (tid & 1)) * TSTEPS + t) * NIN;
            xv0 = xp[0]; xv1 = xp[1]; xv2 = xp[2];
        }

        if (t < TSTEPS) {
            // ---- wave-local h window reassembly from hstage (wave-lockstep,
            // compiler inserts the lgkmcnt) — no barrier. Broadcast + 2-way.
            const uint4* hwA = (const uint4*)&hstage[par][0][(w << 6) + (kslot << 3)];
            const uint4* hwB = (const uint4*)&hstage[par][1][(w << 6) + (kslot << 3)];
            const uint4 hA0 = hwA[0], hA1 = hwA[1];
            const uint4 hB0 = hwB[0], hB1 = hwB[1];

            // ---- partial dot: rows [8*rgrp..+8), k [256w+32*kslot..+32)
            // slot(G) = G ^ rgrp (bits 0-2): lanes tile all 32 banks.
            int acc[8][2];
#pragma unroll
            for (int rr = 0; rr < 8; ++rr) { acc[rr][0] = 0; acc[rr][1] = 0; }
            const uint4* w4p = (const uint4*)wlds;
            const int g0 = (w << 4) + (((kslot << 1) ^ rgrp) & 15);
#pragma unroll
            for (int rr = 0; rr < 8; ++rr) {
                const int gi = (((rgrp << 3) + rr) << 7);
                uint4 w0 = w4p[gi + g0];
                uint4 w1 = w4p[gi + (g0 ^ 1)];
                acc[rr][0] = dot16(w0, hA0, acc[rr][0]);
                acc[rr][0] = dot16(w1, hA1, acc[rr][0]);
                acc[rr][1] = dot16(w0, hB0, acc[rr][1]);
                acc[rr][1] = dot16(w1, hB1, acc[rr][1]);
            }
            // ---- fold kslot (lane bits 3..5); int add order-exact
#pragma unroll
            for (int rr = 0; rr < 8; ++rr)
#pragma unroll
                for (int b = 0; b < 2; ++b) {
                    int a = acc[rr][b];
                    a += __shfl_xor(a, 8, 64);
                    a += __shfl_xor(a, 16, 64);
                    a += __shfl_xor(a, 32, 64);
                    acc[rr][b] = a;
                }
            if (lane < 8) {                          // lane == rgrp, kslot 0
#pragma unroll
                for (int rr = 0; rr < 8; ++rr) {
                    red[par][w][lane][(rr << 1)]     = acc[rr][0];
                    red[par][w][lane][(rr << 1) + 1] = acc[rr][1];
                }
            }
        }
        __syncthreads();                             // the ONE barrier/step

        // ---- waves 0-1: final 8-way sum, tanh, tagged stores ----
        if (t < TSTEPS && tid < 128) {
            const int br = tid >> 1;                 // in-block row 0..63
            const int b  = tid & 1;
            int s = 0;
#pragma unroll
            for (int wp = 0; wp < 8; ++wp)
                s += red[par][wp][br >> 3][((br & 7) << 1) + b];
            float pre = (float)s * wscale[br] * (1.f / 127.f)
                      + wn0 * xv0 + wn1 * xv1 + wn2 * xv2;
            const int qv = q8(tanhf(pre) * 127.f);
            // pack rows (2u,2u+1) of batch bb into one tagged dword
            const int qlo = __shfl(qv, ((lane >> 1) << 2) + (lane & 1), 64);
            const int qhi = __shfl(qv, ((lane >> 1) << 2) + 2 + (lane & 1), 64);
            if (lane < 32) {
                const int bb = lane & 1;
                const int u  = (w << 4) + (lane >> 1);   // 0..31 strip dword
                unsigned dv = (unsigned)(qlo & 0xff) |
                              ((unsigned)(qhi & 0xff) << 8) | (tg1 << 16);
                st1_uc(hbn + g * 2048 + bb * 1024 + rg * 32 + u, dv);
            }
        }

        // ---- cross-step prefetch of next window (tag check absorbs stale) ----
        if (t < TSTEPS) {
            const unsigned* nA = hbn + g * 2048 +        128 * w + 2 * lane;
            const unsigned* nB = hbn + g * 2048 + 1024 + 128 * w + 2 * lane;
            asm volatile("global_load_dwordx2 %0, %2, off sc0 sc1\n\t"
                         "global_load_dwordx2 %1, %3, off sc0 sc1"
                         : "=&v"(ta), "=&v"(tb) : "v"(nA), "v"(nB) : "memory");
        }

        // ---- waves 2-7: rotating projection (parallel with final/store)
        if (t > 0 && rg == ((t - 1) & 31) && w >= 2) {
            const int pw = w - 2;                    // 0..5
            const int b  = pw / NOUT;                // 0..1
            const int k  = pw % NOUT;                // 0..2
            const float4* wo4 = (const float4*)(Wout + (size_t)k * RDIM);
            float a = 0.f;
#pragma unroll
            for (int j = 0; j < 8; ++j) {
                unsigned hv = hstage[par][b][(lane << 3) + j];
                float4 wf = wo4[(lane << 3) + j];
                a += (float)(int)(signed char)(hv & 0xff)         * wf.x;
                a += (float)(int)(signed char)((hv >> 8) & 0xff)  * wf.y;
                a += (float)(int)(signed char)((hv >> 16) & 0xff) * wf.z;
                a += (float)(int)(signed char)(hv >> 24)          * wf.w;
            }
#pragma unroll
            for (int off = 32; off >= 1; off >>= 1)
                a += __shfl_xor(a, off, 64);
            if (lane == 0)
                out[((size_t)(b0 + b) * TSTEPS + (t - 1)) * NOUT + k] =
                    a * (1.f / 127.f) + bout[k];
        }
        // WAR safety unchanged from r24: parity double-buffering + the
        // per-step barrier order all red/hstage read-write pairs.
    }
}

extern "C" void kernel_launch(void* const* d_in, const int* in_sizes, int n_in,
                              void* d_out, int out_size, void* d_ws, size_t ws_size,
                              hipStream_t stream) {
    const float* x    = (const float*)d_in[0];
    const float* Win  = (const float*)d_in[1];
    const float* W    = (const float*)d_in[2];
    const float* Wout = (const float*)d_in[3];
    const float* bout = (const float*)d_in[4];
    float* out = (float*)d_out;
    unsigned* wsu = (unsigned*)d_ws;

    // zero tagged-h buffers (tag0 + zero payload = valid h0), ~128 KB
    hipMemsetAsync(d_ws, 0, (size_t)WS_USED_DW * sizeof(unsigned), stream);

    // allow 128 KB dynamic LDS (idempotent; same work every call)
    hipFuncSetAttribute((const void*)esn_persist,
                        hipFuncAttributeMaxDynamicSharedMemorySize, 131072);

    void* args[] = {(void*)&W, (void*)&Win, (void*)&x, (void*)&Wout, (void*)&bout,
                    (void*)&wsu, (void*)&out};
    hipError_t e = hipLaunchCooperativeKernel((const void*)esn_persist,
                                              dim3(NBLK), dim3(NTHR),
                                              args, 131072, stream);
    if (e != hipSuccess) {
        // Fallback: plain launch (256 blocks, 1/CU with ~150KB LDS -> all
        // co-resident; bounded spins guarantee no hang regardless).
        esn_persist<<<dim3(NBLK), dim3(NTHR), 131072, stream>>>(
            W, Win, x, Wout, bout, wsu, out);
    }
}

// Round 9
// 6280.056 us; speedup vs baseline: 1.0848x; 1.0848x over previous
//
#include <hip/hip_runtime.h>
#include <math.h>

// ESN reservoir, persistent kernel, round 27 = r26 resubmit (r26 died to an
// infra container failure, not a kernel verdict; no counters returned).
// Only change vs r26: POLL_MAX tightened 1<<16 -> 1<<14 (worst-case gate
// time with per-round s_sleep(2) stays ~20ms, far beyond any real skew,
// keeps the broken-protocol worst case well under any watchdog).
//
// r26 design (untested, predictions stand):
//  1. Cross-step prefetch issued at END of loop body (after tagged stores +
//     projection), preceded by a wave-uniform ADAPTIVE sleep: first-check
//     all-hit -> dly-=1, miss -> dly+=4, clamp [0,24] (x64cy). Each wave
//     tunes to its own 4 producers' skew. Converged: first check hits =>
//     detect ~0. Worst case = r25 (tag check absorbs staleness).
//  2. Poll backoff: s_sleep(2) from round 2 (was round 65) — cuts MALL
//     poll spam (a cross-block jitter source).
//
// Everything else r25-verbatim: tagged protocol (dword = 2x int8 + tag16;
// dword-store atomicity certifies payload; memset tag0 = valid h0),
// per-lane single-producer poll, k-split waves, W LDS swizzle, ONE
// __syncthreads/step, waves 0-1 final+tanh+tagged stores, waves 2-7
// rotating projection, parity double-buffered red/hstage, bounded spins
// (never hang), int32 dot exact => bit-identical h trajectory.

#define RDIM   2048
#define BATCH  16
#define TSTEPS 2048
#define NIN    3
#define NOUT   3
#define NBLK   256
#define NTHR   512

typedef unsigned u32x2 __attribute__((ext_vector_type(2)));

// workspace layout (dwords)
#define HT0_DW     0            // [8 groups][2 batches][1024] tagged h dwords
#define HT1_DW     16384
#define WS_USED_DW 32768

#define POLL_MAX   (1L << 14)

__device__ __forceinline__ void st1_uc(unsigned* p, unsigned v) {
    asm volatile("global_store_dword %0, %1, off sc0 sc1" :: "v"(p), "v"(v) : "memory");
}

__device__ __forceinline__ int q8(float v) {          // round, clamp [-127,127]
    float c = fminf(127.f, fmaxf(-127.f, v));
    return (int)__builtin_rintf(c);
}
__device__ __forceinline__ unsigned pack4(int a, int b, int c, int d) {
    return (a & 0xff) | ((b & 0xff) << 8) | ((c & 0xff) << 16) | ((d & 0xff) << 24);
}
__device__ __forceinline__ int dot4i(unsigned a, unsigned b, int c) {
#if __has_builtin(__builtin_amdgcn_sdot4)
    return __builtin_amdgcn_sdot4((int)a, (int)b, c, false);
#else
    c += (int)(signed char)(a) * (int)(signed char)(b);
    c += (int)(signed char)(a >> 8)  * (int)(signed char)(b >> 8);
    c += (int)(signed char)(a >> 16) * (int)(signed char)(b >> 16);
    c += (int)(signed char)(a >> 24) * (int)(signed char)(b >> 24);
    return c;
#endif
}
__device__ __forceinline__ int dot16(uint4 wq, uint4 hq, int c) {
    c = dot4i(wq.x, hq.x, c);
    c = dot4i(wq.y, hq.y, c);
    c = dot4i(wq.z, hq.z, c);
    c = dot4i(wq.w, hq.w, c);
    return c;
}

extern "C" __global__ void __launch_bounds__(NTHR, 1) esn_persist(
    const float* __restrict__ W,       // [R,R] fp32
    const float* __restrict__ Win,     // [R,3]
    const float* __restrict__ x,       // [B,T,3]
    const float* __restrict__ Wout,    // [3,R]
    const float* __restrict__ bout,    // [3]
    unsigned* wsu,                     // workspace (dwords, see layout)
    float* __restrict__ out)           // [B,T,3]
{
    __shared__ int red[2][8][8][17];               // [par][wave][rgrp][rr*2+b] padded
    __shared__ __align__(16) unsigned hstage[2][2][512];  // [par][batch][payload dw]
    __shared__ float wscale[64];                   // per-row W scale (m/127)
    extern __shared__ unsigned wlds[];             // 128 KB: W int8, swizzled granules

    const int tid  = threadIdx.x;
    const int lane = tid & 63;
    const int w    = tid >> 6;               // wave 0..7
    const int blk  = blockIdx.x;
    const int rg   = blk & 31;               // rows rg*64..+64
    const int g    = blk >> 5;               // batches g*2..+2
    const int b0    = g * 2;
    const int kslot = lane >> 3;             // 0..7: k sub-slice within wave
    const int rgrp  = lane & 7;              // 0..7: row octet within block

    // ---- one-time: quantize W rows -> LDS int8 (per-row scale), swizzled ----
    // granule G of in-block row r stored at slot G ^ ((r>>3)&7); here r>>3 == w.
#pragma unroll
    for (int rr = 0; rr < 8; ++rr) {
        const int   row = rg * 64 + w * 8 + rr;
        const float4* Wr = (const float4*)(W + (size_t)row * RDIM);
        float m = 0.f;
#pragma unroll
        for (int j = 0; j < 8; ++j) {        // lane covers 8 float4 = 32 elems
            float4 v = Wr[j * 64 + lane];
            m = fmaxf(m, fmaxf(fmaxf(fabsf(v.x), fabsf(v.y)),
                               fmaxf(fabsf(v.z), fabsf(v.w))));
        }
#pragma unroll
        for (int off = 32; off >= 1; off >>= 1)
            m = fmaxf(m, __shfl_xor(m, off, 64));
        const float inv = (m > 0.f) ? 127.f / m : 0.f;
        if (lane == 0) wscale[w * 8 + rr] = (m > 0.f) ? m / 127.f : 0.f;
#pragma unroll
        for (int j = 0; j < 8; ++j) {
            float4 v = Wr[j * 64 + lane];
            const int gsw = (j * 16 + (lane >> 2)) ^ w;          // bits 0-2 XOR
            wlds[(w * 8 + rr) * 512 + gsw * 4 + (lane & 3)] =
                pack4(q8(v.x * inv), q8(v.y * inv), q8(v.z * inv), q8(v.w * inv));
        }
    }

    // ---- hoist Win (loop-invariant per final-thread) ----
    float wn0 = 0.f, wn1 = 0.f, wn2 = 0.f;
    if (tid < 128) {
        const float* wp = Win + (size_t)(rg * 64 + (tid >> 1)) * NIN;
        wn0 = wp[0]; wn1 = wp[1]; wn2 = wp[2];
    }
    __syncthreads();

    unsigned* const ht0 = wsu + HT0_DW;
    unsigned* const ht1 = wsu + HT1_DW;

    // persistent poll regs; bootstrap prefetch (memset zeros = tag0 = h0)
    u32x2 ta, tb;
    {
        const unsigned* pA0 = ht0 + g * 2048 +        128 * w + 2 * lane;
        const unsigned* pB0 = ht0 + g * 2048 + 1024 + 128 * w + 2 * lane;
        asm volatile("global_load_dwordx2 %0, %2, off sc0 sc1\n\t"
                     "global_load_dwordx2 %1, %3, off sc0 sc1"
                     : "=&v"(ta), "=&v"(tb) : "v"(pA0), "v"(pB0) : "memory");
    }
    int dly = 6;                                     // adaptive issue delay (x64cy)

    for (int t = 0; t <= TSTEPS; ++t) {
        unsigned* const hb  = (t & 1) ? ht1 : ht0;   // tags == t live here
        unsigned* const hbn = (t & 1) ? ht0 : ht1;   // t+1 stores go here
        const unsigned tg  = (unsigned)t & 0xffffu;
        const unsigned tg1 = (unsigned)(t + 1) & 0xffffu;
        const int par = t & 1;

        // ---- poll: check-first on prefetched regs; reload only on miss ----
        bool first_hit;
        {
            const unsigned* pA = hb + g * 2048 +        128 * w + 2 * lane;
            const unsigned* pB = hb + g * 2048 + 1024 + 128 * w + 2 * lane;
            asm volatile("s_waitcnt vmcnt(0)" : "+v"(ta), "+v"(tb) :: "memory");
            bool ok = (ta[0] >> 16) == tg && (ta[1] >> 16) == tg &&
                      (tb[0] >> 16) == tg && (tb[1] >> 16) == tg;
            first_hit = ok;
            long r = 0;
            while (!ok && r <= POLL_MAX) {           // per-lane; never hangs
                ++r;
                if (r > 1) __builtin_amdgcn_s_sleep(2);
                asm volatile("global_load_dwordx2 %0, %2, off sc0 sc1\n\t"
                             "global_load_dwordx2 %1, %3, off sc0 sc1\n\t"
                             "s_waitcnt vmcnt(0)"
                             : "=&v"(ta), "=&v"(tb) : "v"(pA), "v"(pB) : "memory");
                ok = (ta[0] >> 16) == tg && (ta[1] >> 16) == tg &&
                     (tb[0] >> 16) == tg && (tb[1] >> 16) == tg;
            }
        }
        // adapt issue delay (wave-uniform: __all -> same update in all lanes)
        dly += __all((int)first_hit) ? -1 : 4;
        dly = dly < 0 ? 0 : (dly > 24 ? 24 : dly);

        // detag: payload dword (4 int8 h values) per batch -> hstage
        const unsigned pdA = (ta[0] & 0xffffu) | (ta[1] << 16);
        const unsigned pdB = (tb[0] & 0xffffu) | (tb[1] << 16);
        hstage[par][0][(w << 6) + lane] = pdA;
        hstage[par][1][(w << 6) + lane] = pdB;

        // ---- x prefetch for the post-barrier final (off the chain) ----
        float xv0 = 0.f, xv1 = 0.f, xv2 = 0.f;
        if (t < TSTEPS && tid < 128) {
            const float* xp = x + ((size_t)(b0 + (tid & 1)) * TSTEPS + t) * NIN;
            xv0 = xp[0]; xv1 = xp[1]; xv2 = xp[2];
        }

        if (t < TSTEPS) {
            // ---- wave-local h window reassembly from hstage (wave-lockstep,
            // compiler inserts the lgkmcnt) — no barrier. Broadcast + 2-way.
            const uint4* hwA = (const uint4*)&hstage[par][0][(w << 6) + (kslot << 3)];
            const uint4* hwB = (const uint4*)&hstage[par][1][(w << 6) + (kslot << 3)];
            const uint4 hA0 = hwA[0], hA1 = hwA[1];
            const uint4 hB0 = hwB[0], hB1 = hwB[1];

            // ---- partial dot: rows [8*rgrp..+8), k [256w+32*kslot..+32)
            int acc[8][2];
#pragma unroll
            for (int rr = 0; rr < 8; ++rr) { acc[rr][0] = 0; acc[rr][1] = 0; }
            const uint4* w4p = (const uint4*)wlds;
            const int g0 = (w << 4) + (((kslot << 1) ^ rgrp) & 15);
#pragma unroll
            for (int rr = 0; rr < 8; ++rr) {
                const int gi = (((rgrp << 3) + rr) << 7);
                uint4 w0 = w4p[gi + g0];
                uint4 w1 = w4p[gi + (g0 ^ 1)];
                acc[rr][0] = dot16(w0, hA0, acc[rr][0]);
                acc[rr][0] = dot16(w1, hA1, acc[rr][0]);
                acc[rr][1] = dot16(w0, hB0, acc[rr][1]);
                acc[rr][1] = dot16(w1, hB1, acc[rr][1]);
            }
            // ---- fold kslot (lane bits 3..5); int add order-exact
#pragma unroll
            for (int rr = 0; rr < 8; ++rr)
#pragma unroll
                for (int b = 0; b < 2; ++b) {
                    int a = acc[rr][b];
                    a += __shfl_xor(a, 8, 64);
                    a += __shfl_xor(a, 16, 64);
                    a += __shfl_xor(a, 32, 64);
                    acc[rr][b] = a;
                }
            if (lane < 8) {                          // lane == rgrp, kslot 0
#pragma unroll
                for (int rr = 0; rr < 8; ++rr) {
                    red[par][w][lane][(rr << 1)]     = acc[rr][0];
                    red[par][w][lane][(rr << 1) + 1] = acc[rr][1];
                }
            }
        }
        __syncthreads();                             // the ONE barrier/step

        // ---- waves 0-1: final 8-way sum, tanh, tagged stores ----
        if (t < TSTEPS && tid < 128) {
            const int br = tid >> 1;                 // in-block row 0..63
            const int b  = tid & 1;
            int s = 0;
#pragma unroll
            for (int wp = 0; wp < 8; ++wp)
                s += red[par][wp][br >> 3][((br & 7) << 1) + b];
            float pre = (float)s * wscale[br] * (1.f / 127.f)
                      + wn0 * xv0 + wn1 * xv1 + wn2 * xv2;
            const int qv = q8(tanhf(pre) * 127.f);
            // pack rows (2u,2u+1) of batch bb into one tagged dword
            const int qlo = __shfl(qv, ((lane >> 1) << 2) + (lane & 1), 64);
            const int qhi = __shfl(qv, ((lane >> 1) << 2) + 2 + (lane & 1), 64);
            if (lane < 32) {
                const int bb = lane & 1;
                const int u  = (w << 4) + (lane >> 1);   // 0..31 strip dword
                unsigned dv = (unsigned)(qlo & 0xff) |
                              ((unsigned)(qhi & 0xff) << 8) | (tg1 << 16);
                st1_uc(hbn + g * 2048 + bb * 1024 + rg * 32 + u, dv);
            }
        }

        // ---- waves 2-7: rotating projection (parallel with final/store)
        if (t > 0 && rg == ((t - 1) & 31) && w >= 2) {
            const int pw = w - 2;                    // 0..5
            const int b  = pw / NOUT;                // 0..1
            const int k  = pw % NOUT;                // 0..2
            const float4* wo4 = (const float4*)(Wout + (size_t)k * RDIM);
            float a = 0.f;
#pragma unroll
            for (int j = 0; j < 8; ++j) {
                unsigned hv = hstage[par][b][(lane << 3) + j];
                float4 wf = wo4[(lane << 3) + j];
                a += (float)(int)(signed char)(hv & 0xff)         * wf.x;
                a += (float)(int)(signed char)((hv >> 8) & 0xff)  * wf.y;
                a += (float)(int)(signed char)((hv >> 16) & 0xff) * wf.z;
                a += (float)(int)(signed char)(hv >> 24)          * wf.w;
            }
#pragma unroll
            for (int off = 32; off >= 1; off >>= 1)
                a += __shfl_xor(a, off, 64);
            if (lane == 0)
                out[((size_t)(b0 + b) * TSTEPS + (t - 1)) * NOUT + k] =
                    a * (1.f / 127.f) + bout[k];
        }

        // ---- adaptive-delay cross-step prefetch (AFTER stores+projection):
        // sleep ~dly*64cy so the sample lands just after producers' stores
        // become visible; tag check absorbs any residual staleness.
        if (t < TSTEPS) {
            for (int i = 0; i < dly; ++i) __builtin_amdgcn_s_sleep(1);
            const unsigned* nA = hbn + g * 2048 +        128 * w + 2 * lane;
            const unsigned* nB = hbn + g * 2048 + 1024 + 128 * w + 2 * lane;
            asm volatile("global_load_dwordx2 %0, %2, off sc0 sc1\n\t"
                         "global_load_dwordx2 %1, %3, off sc0 sc1"
                         : "=&v"(ta), "=&v"(tb) : "v"(nA), "v"(nB) : "memory");
        }
        // WAR safety unchanged from r24: parity double-buffering + the
        // per-step barrier order all red/hstage read-write pairs.
    }
}

extern "C" void kernel_launch(void* const* d_in, const int* in_sizes, int n_in,
                              void* d_out, int out_size, void* d_ws, size_t ws_size,
                              hipStream_t stream) {
    const float* x    = (const float*)d_in[0];
    const float* Win  = (const float*)d_in[1];
    const float* W    = (const float*)d_in[2];
    const float* Wout = (const float*)d_in[3];
    const float* bout = (const float*)d_in[4];
    float* out = (float*)d_out;
    unsigned* wsu = (unsigned*)d_ws;

    // zero tagged-h buffers (tag0 + zero payload = valid h0), ~128 KB
    hipMemsetAsync(d_ws, 0, (size_t)WS_USED_DW * sizeof(unsigned), stream);

    // allow 128 KB dynamic LDS (idempotent; same work every call)
    hipFuncSetAttribute((const void*)esn_persist,
                        hipFuncAttributeMaxDynamicSharedMemorySize, 131072);

    void* args[] = {(void*)&W, (void*)&Win, (void*)&x, (void*)&Wout, (void*)&bout,
                    (void*)&wsu, (void*)&out};
    hipError_t e = hipLaunchCooperativeKernel((const void*)esn_persist,
                                              dim3(NBLK), dim3(NTHR),
                                              args, 131072, stream);
    if (e != hipSuccess) {
        // Fallback: plain launch (256 blocks, 1/CU with ~150KB LDS -> all
        // co-resident; bounded spins guarantee no hang regardless).
        esn_persist<<<dim3(NBLK), dim3(NTHR), 131072, stream>>>(
            W, Win, x, Wout, bout, wsu, out);
    }
}